// Round 21
// baseline (120.054 us; speedup 1.0000x reference)
//
#include <hip/hip_runtime.h>

typedef unsigned int u32;
typedef __attribute__((ext_vector_type(8))) _Float16 half8v;
typedef __attribute__((ext_vector_type(4))) u32 u32x4;
typedef __attribute__((ext_vector_type(4))) float f32x4;

#define NPB 32           // nodes per bucket (sort + aggregation, single level)
#define SH  5
#define CHP 4096         // edges per chunk (hist + scatter)

// order-preserving float<->uint encoding; enc never returns 0 for real values
__device__ __forceinline__ u32 enc_f32(float f) {
    u32 b = __float_as_uint(f);
    return (b & 0x80000000u) ? ~b : (b | 0x80000000u);
}
__device__ __forceinline__ float dec_f32(u32 u) {
    u32 b = (u & 0x80000000u) ? (u & 0x7FFFFFFFu) : ~u;
    return __uint_as_float(b);
}
// packed f16: r = max(a+b, 0) per half  (2 VALU ops)
__device__ __forceinline__ u32 pk_addrelu(u32 a, u32 b) {
    u32 r;
    asm("v_pk_add_f16 %0, %1, %2\n\tv_pk_max_f16 %0, %0, 0"
        : "=v"(r) : "v"(a), "v"(b));
    return r;
}
__device__ __forceinline__ u32 pkrtz(float lo, float hi) {
    auto h = __builtin_amdgcn_cvt_pkrtz(lo, hi);   // __fp16 ext_vector(2)
    return __builtin_bit_cast(u32, h);
}

// ---------- K_pq_hist: [0,npc) per-chunk 32-bucket hist g1; [npc,..) PQ tables (f16-packed) ----------
__global__ __launch_bounds__(256) void k_pq_hist(
    const float* __restrict__ x, const float* __restrict__ W1, const float* __restrict__ b1,
    const int* __restrict__ ei,
    u32* __restrict__ Pb, u32* __restrict__ Qb, u32* __restrict__ g1,
    int N, int E, int NSB, int npc)
{
    __shared__ u32 smem[4224];     // 16.9 KB, aliased by both roles
    int tid = threadIdx.x;
    int bid = (int)blockIdx.x;

    if (bid < npc) {
        // ---- g1 hist role (NSB <= 4224 guaranteed by host) ----
        u32* cnt = smem;
        for (int s = tid; s < NSB; s += 256) cnt[s] = 0;
        __syncthreads();
        int s0 = bid * CHP, end = min(E, s0 + CHP);
        int nq = (end - s0) >> 2;  // host guarantees E%4==0
        const int4* d4p = (const int4*)(ei + (size_t)E + s0);
        for (int qi = tid; qi < nq; qi += 256) {
            int4 d4 = d4p[qi];
            atomicAdd(&cnt[d4.x >> SH], 1u);
            atomicAdd(&cnt[d4.y >> SH], 1u);
            atomicAdd(&cnt[d4.z >> SH], 1u);
            atomicAdd(&cnt[d4.w >> SH], 1u);
        }
        __syncthreads();
        for (int s = tid; s < NSB; s += 256) g1[(size_t)s * npc + bid] = cnt[s];
        return;
    }

    // ---- PQ role ----
    float* sWTa = (float*)smem;            // [j][k] = W1[k][j]-W1[k+32][j]
    float* sWTb = (float*)smem + 2048;     // [j][k] = W1[k+32][j]
    for (int idx = tid; idx < 2048; idx += 256) {
        int j = idx >> 5, k = idx & 31;
        float a = W1[k * 64 + j];
        float b = W1[(k + 32) * 64 + j];
        sWTa[j * 32 + k] = a - b;
        sWTb[j * 32 + k] = b;
    }
    __syncthreads();

    int blk = bid - npc;
    int n = blk * 256 + tid;

    u32 pw[32], qw[32];
    if (n < N) {
        float xr[32];
        const float4* x4 = reinterpret_cast<const float4*>(x + (size_t)n * 32);
#pragma unroll
        for (int q = 0; q < 8; ++q) {
            float4 v = x4[q];
            xr[4 * q] = v.x; xr[4 * q + 1] = v.y; xr[4 * q + 2] = v.z; xr[4 * q + 3] = v.w;
        }
        for (int j0 = 0; j0 < 64; j0 += 2) {
            float pv[2], qv[2];
#pragma unroll
            for (int m = 0; m < 2; ++m) {
                int j = j0 + m;
                float a = b1[j], q = 0.f;
                const f32x4* wa4 = (const f32x4*)(sWTa + j * 32);
                const f32x4* wb4 = (const f32x4*)(sWTb + j * 32);
#pragma unroll
                for (int k4 = 0; k4 < 8; ++k4) {
                    f32x4 wa = wa4[k4];
                    f32x4 wb = wb4[k4];
#pragma unroll
                    for (int e = 0; e < 4; ++e) {
                        a = fmaf(xr[4 * k4 + e], wa[e], a);
                        q = fmaf(xr[4 * k4 + e], wb[e], q);
                    }
                }
                pv[m] = a; qv[m] = q;
            }
            pw[j0 >> 1] = pkrtz(pv[0], pv[1]);
            qw[j0 >> 1] = pkrtz(qv[0], qv[1]);
        }
    }
    __syncthreads();   // weights dead; smem re-used as staging

    u32* sP = smem;            // [64][33] padded
    u32* sQ = smem + 2112;
    for (int r = 0; r < 4; ++r) {
        if ((tid >> 6) == r && n < N) {
            int row = tid & 63;
#pragma unroll
            for (int i = 0; i < 32; ++i) {
                sP[row * 33 + i] = pw[i];
                sQ[row * 33 + i] = qw[i];
            }
        }
        __syncthreads();
        int nodebase = blk * 256 + r * 64;
        size_t wbase = (size_t)nodebase * 32;
        for (int w = tid; w < 2048; w += 256) {
            int node = nodebase + (w >> 5);
            if (node < N) {
                u32 v = sP[(w >> 5) * 33 + (w & 31)];
                u32 u = sQ[(w >> 5) * 33 + (w & 31)];
                Pb[wbase + w] = v;
                Qb[wbase + w] = u;
            }
        }
        __syncthreads();
    }
}

// ---------- partial scan, 2048 items/block (8/thread) + looping block-sum scan ----------
__global__ __launch_bounds__(256) void k_scan1(const u32* __restrict__ deg, u32* __restrict__ cursor,
                                               u32* __restrict__ bsum, int M) {
    __shared__ u32 sh[256];
    int t = threadIdx.x;
    int base = blockIdx.x * 2048 + t * 8;
    u32 v[8];
    if (base + 7 < M) {
        uint4 a = *reinterpret_cast<const uint4*>(deg + base);
        uint4 b = *reinterpret_cast<const uint4*>(deg + base + 4);
        v[0] = a.x; v[1] = a.y; v[2] = a.z; v[3] = a.w;
        v[4] = b.x; v[5] = b.y; v[6] = b.z; v[7] = b.w;
    } else {
#pragma unroll
        for (int i = 0; i < 8; ++i) v[i] = (base + i < M) ? deg[base + i] : 0;
    }
    u32 s = 0;
#pragma unroll
    for (int i = 0; i < 8; ++i) s += v[i];
    sh[t] = s; __syncthreads();
    u32 acc = s;
    for (int off = 1; off < 256; off <<= 1) {
        u32 add = (t >= off) ? sh[t - off] : 0;
        __syncthreads();
        acc += add; sh[t] = acc;
        __syncthreads();
    }
    u32 run = acc - s;
#pragma unroll
    for (int i = 0; i < 8; ++i) {
        if (base + i < M) cursor[base + i] = run;
        run += v[i];
    }
    if (t == 255) bsum[blockIdx.x] = acc;
}

// exclusive scan of bsum[nb] -> bsumX[nb], nb up to 1024 (looping, carry)
__global__ __launch_bounds__(256) void k_scan2(const u32* __restrict__ bsum, u32* __restrict__ bsumX, int nb) {
    __shared__ u32 sh[256];
    __shared__ u32 carry;
    int t = threadIdx.x;
    if (t == 0) carry = 0;
    __syncthreads();
    for (int r0 = 0; r0 < nb; r0 += 256) {
        int i = r0 + t;
        u32 v = (i < nb) ? bsum[i] : 0;
        sh[t] = v; __syncthreads();
        u32 acc = v;
        for (int off = 1; off < 256; off <<= 1) {
            u32 add = (t >= off) ? sh[t - off] : 0;
            __syncthreads();
            acc += add; sh[t] = acc;
            __syncthreads();
        }
        if (i < nb) bsumX[i] = carry + acc - v;
        __syncthreads();
        if (t == 255) carry += acc;
        __syncthreads();
    }
}

// ---------- K_sp1: 1024-thread blocks, scatter src|local5<<17 directly into 32-buckets ----------
__global__ __launch_bounds__(1024) void k_sp1(const int* __restrict__ ei,
                                              const u32* __restrict__ g1cur, const u32* __restrict__ bsumX1,
                                              u32* __restrict__ sorted, int E, int NSB, int npc) {
    __shared__ u32 sb[3328], cnt[3328];
    int tid = threadIdx.x;
    int c = (int)blockIdx.x;
    for (int s = tid; s < NSB; s += 1024) {
        size_t idx = (size_t)s * npc + c;
        sb[s] = g1cur[idx] + bsumX1[idx >> 11];
        cnt[s] = 0;
    }
    __syncthreads();
    int s0 = c * CHP, end = min(E, s0 + CHP);
    int nq = (end - s0) >> 2;
    const int4* d4p = (const int4*)(ei + (size_t)E + s0);
    const int4* s4p = (const int4*)(ei + s0);
    for (int qi = tid; qi < nq; qi += 1024) {
        int4 d4 = d4p[qi];
        int4 s4 = s4p[qi];
        int dd[4] = {d4.x, d4.y, d4.z, d4.w};
        int ss[4] = {s4.x, s4.y, s4.z, s4.w};
#pragma unroll
        for (int u = 0; u < 4; ++u) {
            int s = dd[u] >> SH;
            u32 r = atomicAdd(&cnt[s], 1u);
            sorted[sb[s] + r] = (u32)ss[u] | ((u32)(dd[u] & (NPB - 1)) << 17);
        }
    }
}

// ---------- K_bucket: one 512-thread block (8 waves) per 32-node bucket ----------
// P rows staged in LDS (XOR-swizzled); depth-2 pipelined Q gather; f16 packed-math h;
// MFMA f16 + LDS max-agg (4KB) + fused decode/store
// A-frag (16x16x32 f16): lane l holds A[row=l&15][k=(l>>4)*8 + j]
// C/D (m89-verified, dtype-independent): lane l, reg i -> D[row=(l>>4)*4+i][col=l&15]
__global__ __launch_bounds__(512) void k_bucket(
    const u32* __restrict__ Pb, const u32* __restrict__ Qb,
    const u32* __restrict__ sorted, const u32* __restrict__ g1cur, const u32* __restrict__ bsumX1,
    const float* __restrict__ W2, const float* __restrict__ b2,
    float* __restrict__ out, int E, int N, int NSB, int npc)
{
    __shared__ u32 agg[NPB * 32];   // 4 KB, encoded-u32 max, 0 = "untouched"
    __shared__ u32 sPb[NPB * 32];   // 4 KB, P rows, group-XOR-swizzled
    int b = (int)blockIdx.x;
    int tid = threadIdx.x;
    int nodebase = b << SH;

    for (int i = tid; i < NPB * 32; i += 512) agg[i] = 0u;
    // stage P rows: group g (4 words) of row loc stored at group (g ^ (loc&7))
    for (int i = tid; i < NPB * 32; i += 512) {
        int loc = i >> 5, w = i & 31;
        int node = nodebase + loc;
        u32 v = (node < N) ? Pb[(size_t)node * 32 + w] : 0u;
        sPb[loc * 32 + ((((w >> 2) ^ (loc & 7)) << 2) | (w & 3))] = v;
    }

    int lane = tid & 63;
    int wid = tid >> 6;            // 0..7
    int n = lane & 15;
    int kc = lane >> 4;

    // W2 resident as 4 f16 B-fragments
    half8v b00, b01, b10, b11;
#pragma unroll
    for (int j = 0; j < 8; ++j) {
        int k = kc * 8 + j;
        b00[j] = (_Float16)W2[k * 32 + n];
        b01[j] = (_Float16)W2[(k + 32) * 32 + n];
        b10[j] = (_Float16)W2[k * 32 + n + 16];
        b11[j] = (_Float16)W2[(k + 32) * 32 + n + 16];
    }

    size_t i0 = (size_t)b * npc;
    u32 start = g1cur[i0] + bsumX1[i0 >> 11];
    u32 bend;
    if (b + 1 < NSB) {
        size_t i1 = (size_t)(b + 1) * npc;
        bend = g1cur[i1] + bsumX1[i1 >> 11];
    } else {
        bend = (u32)E;
    }
    int ntiles = ((int)(bend - start) + 15) >> 4;

    __syncthreads();   // agg + sPb ready

    int t = wid;
    u32 slotA = start + (u32)t * 16u + (u32)n;
    u32 recA = 0;
    uint4 qA0, qA1;
    if (t < ntiles) {   // wave-uniform branch
        u32 sl = slotA < bend ? slotA : bend - 1;
        recA = sorted[sl];
        int src = (int)(recA & 0x1FFFFu);
        const u32* qr = Qb + (size_t)src * 32;
        qA0 = *(const uint4*)(qr + kc * 4);
        qA1 = *(const uint4*)(qr + 16 + kc * 4);
    }

    for (; t < ntiles; t += 8) {
        // ---- prefetch next tile's rec + Q for this wave (clamped-safe) ----
        u32 slotB = start + (u32)(t + 8) * 16u + (u32)n;
        u32 slB = slotB < bend ? slotB : bend - 1;
        u32 recB = sorted[slB];
        int srcB = (int)(recB & 0x1FFFFu);
        const u32* qrB = Qb + (size_t)srcB * 32;
        uint4 qB0 = *(const uint4*)(qrB + kc * 4);
        uint4 qB1 = *(const uint4*)(qrB + 16 + kc * 4);

        // ---- compute current tile ----
        bool valid = slotA < bend;
        int locA = (int)(recA >> 17);
        int local = valid ? locA : -1;

        // P from LDS (swizzled groups; 16 lanes spread over 8 bank-groups)
        const u32* pr = sPb + locA * 32;
        uint4 pA0 = *(const uint4*)(pr + ((kc ^ (locA & 7)) << 2));
        uint4 pA1 = *(const uint4*)(pr + (((4 + kc) ^ (locA & 7)) << 2));

        // h = ReLU(P + Q) in packed f16: 2 VALU per u32
        u32x4 aw0, aw1;
        aw0[0] = pk_addrelu(pA0.x, qA0.x);
        aw0[1] = pk_addrelu(pA0.y, qA0.y);
        aw0[2] = pk_addrelu(pA0.z, qA0.z);
        aw0[3] = pk_addrelu(pA0.w, qA0.w);
        aw1[0] = pk_addrelu(pA1.x, qA1.x);
        aw1[1] = pk_addrelu(pA1.y, qA1.y);
        aw1[2] = pk_addrelu(pA1.z, qA1.z);
        aw1[3] = pk_addrelu(pA1.w, qA1.w);
        half8v a0 = __builtin_bit_cast(half8v, aw0);
        half8v a1 = __builtin_bit_cast(half8v, aw1);

        f32x4 d0 = {0.f, 0.f, 0.f, 0.f};
        f32x4 d1 = {0.f, 0.f, 0.f, 0.f};
        d0 = __builtin_amdgcn_mfma_f32_16x16x32_f16(a0, b00, d0, 0, 0, 0);
        d0 = __builtin_amdgcn_mfma_f32_16x16x32_f16(a1, b01, d0, 0, 0, 0);
        d1 = __builtin_amdgcn_mfma_f32_16x16x32_f16(a0, b10, d1, 0, 0, 0);
        d1 = __builtin_amdgcn_mfma_f32_16x16x32_f16(a1, b11, d1, 0, 0, 0);

        // rows owned by this lane: r = kc*4 + i; row r's record lives in lane r
#pragma unroll
        for (int i = 0; i < 4; ++i) {
            int r = kc * 4 + i;
            int lr = __shfl(local, r, 64);
            if (lr >= 0) {
                int sw = (lr & 1) << 4;
                atomicMax(&agg[(lr << 5) + (n ^ sw)], enc_f32(d0[i]));
                atomicMax(&agg[(lr << 5) + ((n + 16) ^ sw)], enc_f32(d1[i]));
            }
        }

        // ---- rotate ----
        slotA = slotB; recA = recB;
        qA0 = qB0; qA1 = qB1;
    }

    __syncthreads();
    // fused decode + b2 + empty->0; exclusive bucket ownership -> plain coalesced store
    for (int i = tid; i < NPB * 32; i += 512) {
        int local = i >> 5, c = i & 31;
        int node = nodebase + local;
        if (node < N) {
            u32 u = agg[(local << 5) + (c ^ ((local & 1) << 4))];
            out[(size_t)node * 32 + c] = u ? (dec_f32(u) + b2[c]) : 0.f;
        }
    }
}

// ---------- fallback (round-1 style) ----------
__global__ __launch_bounds__(256) void fb_edge(const float* __restrict__ x, const int* __restrict__ ei,
                                               const float* __restrict__ W1, const float* __restrict__ b1,
                                               const float* __restrict__ W2, const float* __restrict__ b2,
                                               u32* __restrict__ out, int E) {
    int e = blockIdx.x * 256 + threadIdx.x;
    if (e >= E) return;
    int src = ei[e], dst = ei[E + e];
    float m[64];
    const float4* xi4 = reinterpret_cast<const float4*>(x + (size_t)dst * 32);
    const float4* xj4 = reinterpret_cast<const float4*>(x + (size_t)src * 32);
#pragma unroll
    for (int q = 0; q < 8; ++q) {
        float4 a = xi4[q], b = xj4[q];
        m[q * 4] = a.x; m[q * 4 + 1] = a.y; m[q * 4 + 2] = a.z; m[q * 4 + 3] = a.w;
        m[32 + q * 4] = b.x - a.x; m[32 + q * 4 + 1] = b.y - a.y;
        m[32 + q * 4 + 2] = b.z - a.z; m[32 + q * 4 + 3] = b.w - a.w;
    }
    float acc[32];
#pragma unroll
    for (int c = 0; c < 32; ++c) acc[c] = b2[c];
    for (int j = 0; j < 64; ++j) {
        float h = b1[j];
#pragma unroll
        for (int k = 0; k < 64; ++k) h = fmaf(m[k], W1[k * 64 + j], h);
        h = fmaxf(h, 0.0f);
#pragma unroll
        for (int c = 0; c < 32; ++c) acc[c] = fmaf(h, W2[j * 32 + c], acc[c]);
    }
    u32* o = out + (size_t)dst * 32;
#pragma unroll
    for (int c = 0; c < 32; ++c) atomicMax(o + c, enc_f32(acc[c]));
}
__global__ __launch_bounds__(256) void fb_decode(u32* __restrict__ buf, int n) {
    int i = blockIdx.x * 256 + threadIdx.x;
    if (i >= n) return;
    u32 u = buf[i];
    reinterpret_cast<float*>(buf)[i] = u ? dec_f32(u) : 0.f;
}

extern "C" void kernel_launch(void* const* d_in, const int* in_sizes, int n_in,
                              void* d_out, int out_size, void* d_ws, size_t ws_size,
                              hipStream_t stream) {
    const float* x  = (const float*)d_in[0];
    const int*   ei = (const int*)d_in[1];
    const float* W1 = (const float*)d_in[2];
    const float* b1 = (const float*)d_in[3];
    const float* W2 = (const float*)d_in[4];
    const float* b2 = (const float*)d_in[5];

    int N = in_sizes[0] / 32;
    int E = in_sizes[1] / 2;
    int NSB = (N + NPB - 1) >> SH;              // 3125 buckets of 32 nodes
    int npc = (E + CHP - 1) / CHP;              // 391 chunks
    int M1  = (int)((size_t)NSB * npc);         // flat hist (1,221,875)
    int nb1 = (M1 + 2047) / 2048;               // 597 scan blocks

    // workspace layout (256B aligned)
    char* ws = (char*)d_ws;
    size_t off = 0;
    auto alloc = [&](size_t bytes) { char* p = ws + off; off += (bytes + 255) & ~(size_t)255; return p; };
    u32*   Pb      = (u32*)alloc((size_t)N * 32 * 4);
    u32*   Qb      = (u32*)alloc((size_t)N * 32 * 4);
    u32*   g1      = (u32*)alloc((size_t)M1 * 4);
    u32*   g1cur   = (u32*)alloc((size_t)M1 * 4);
    u32*   bsum1   = (u32*)alloc(1024 * 4);
    u32*   bsumX1  = (u32*)alloc(1024 * 4);
    u32*   sorted  = (u32*)alloc((size_t)E * 4);
    // guards: LDS table sizes (hist 4224, sp1 3328), 17b src, quad streams, scan width
    bool fits = (off <= ws_size) && (NSB <= 3328) &&
                (N < (1 << 17)) && ((E & 3) == 0) && (nb1 <= 1024);

    if (!fits) {
        hipMemsetAsync(d_out, 0, (size_t)out_size * 4, stream);
        int be = (E + 255) / 256;
        fb_edge<<<be, 256, 0, stream>>>(x, ei, W1, b1, W2, b2, (u32*)d_out, E);
        fb_decode<<<(out_size + 255) / 256, 256, 0, stream>>>((u32*)d_out, out_size);
        return;
    }

    int pq_blocks = (N + 255) / 256;
    k_pq_hist<<<npc + pq_blocks, 256, 0, stream>>>(x, W1, b1, ei, Pb, Qb, g1, N, E, NSB, npc);

    k_scan1<<<nb1, 256, 0, stream>>>(g1, g1cur, bsum1, M1);
    k_scan2<<<1, 256, 0, stream>>>(bsum1, bsumX1, nb1);

    k_sp1<<<npc, 1024, 0, stream>>>(ei, g1cur, bsumX1, sorted, E, NSB, npc);

    k_bucket<<<NSB, 512, 0, stream>>>(Pb, Qb, sorted, g1cur, bsumX1, W2, b2,
                                      (float*)d_out, E, N, NSB, npc);
}

// Round 22
// 104.755 us; speedup vs baseline: 1.1460x; 1.1460x over previous
//
#include <hip/hip_runtime.h>

typedef unsigned int u32;
typedef __attribute__((ext_vector_type(8))) _Float16 half8v;
typedef __attribute__((ext_vector_type(4))) u32 u32x4;
typedef __attribute__((ext_vector_type(4))) float f32x4;

#define NPB1 128         // sort-level-1 bucket (coalesced scatter)
#define SH1  7
#define NPB2 32          // sort-level-2 / aggregation bucket
#define SH2  5
#define CHP  4096        // edges per chunk (hist + scatter)

// order-preserving float<->uint encoding; enc never returns 0 for real values
__device__ __forceinline__ u32 enc_f32(float f) {
    u32 b = __float_as_uint(f);
    return (b & 0x80000000u) ? ~b : (b | 0x80000000u);
}
__device__ __forceinline__ float dec_f32(u32 u) {
    u32 b = (u & 0x80000000u) ? (u & 0x7FFFFFFFu) : ~u;
    return __uint_as_float(b);
}
// packed f16: r = max(a+b, 0) per half  (2 VALU ops)
__device__ __forceinline__ u32 pk_addrelu(u32 a, u32 b) {
    u32 r;
    asm("v_pk_add_f16 %0, %1, %2\n\tv_pk_max_f16 %0, %0, 0"
        : "=v"(r) : "v"(a), "v"(b));
    return r;
}
__device__ __forceinline__ u32 pkrtz(float lo, float hi) {
    auto h = __builtin_amdgcn_cvt_pkrtz(lo, hi);   // __fp16 ext_vector(2)
    return __builtin_bit_cast(u32, h);
}

// ---------- K_pq_hist: [0,npc) per-chunk 128-bucket hist g1; [npc,..) PQ tables (f16) ----------
// PQ role is j-split: block (nodeblk, jhalf) computes 32 of 64 hidden units for 256 nodes.
__global__ __launch_bounds__(256) void k_pq_hist(
    const float* __restrict__ x, const float* __restrict__ W1, const float* __restrict__ b1,
    const int* __restrict__ ei,
    u32* __restrict__ Pb, u32* __restrict__ Qb, u32* __restrict__ g1,
    int N, int E, int NSB1, int npc)
{
    __shared__ u32 smem[4224];     // 16.9 KB worst-case (hist); PQ uses 8.5 KB
    int tid = threadIdx.x;
    int bid = (int)blockIdx.x;

    if (bid < npc) {
        // ---- g1 hist role ----
        u32* cnt = smem;           // [NSB1]
        for (int s = tid; s < NSB1; s += 256) cnt[s] = 0;
        __syncthreads();
        int s0 = bid * CHP, end = min(E, s0 + CHP);
        int nq = (end - s0) >> 2;  // host guarantees E%4==0
        const int4* d4p = (const int4*)(ei + (size_t)E + s0);
        for (int qi = tid; qi < nq; qi += 256) {
            int4 d4 = d4p[qi];
            atomicAdd(&cnt[d4.x >> SH1], 1u);
            atomicAdd(&cnt[d4.y >> SH1], 1u);
            atomicAdd(&cnt[d4.z >> SH1], 1u);
            atomicAdd(&cnt[d4.w >> SH1], 1u);
        }
        __syncthreads();
        for (int s = tid; s < NSB1; s += 256) g1[(size_t)s * npc + bid] = cnt[s];
        return;
    }

    // ---- PQ role (j-split) ----
    int blk = bid - npc;
    int jhalf = blk & 1;           // which 32 of the 64 hidden units
    int nodeblk = blk >> 1;
    int jbase = jhalf * 32;

    float* sWTa = (float*)smem;            // [32][32]: j in [jbase, jbase+32)
    float* sWTb = (float*)smem + 1024;
    for (int idx = tid; idx < 1024; idx += 256) {
        int j = jbase + (idx >> 5), k = idx & 31;
        float a = W1[k * 64 + j];
        float b = W1[(k + 32) * 64 + j];
        sWTa[(idx >> 5) * 32 + k] = a - b;
        sWTb[(idx >> 5) * 32 + k] = b;
    }
    __syncthreads();

    int n = nodeblk * 256 + tid;

    u32 pw[16], qw[16];
    if (n < N) {
        float xr[32];
        const float4* x4 = reinterpret_cast<const float4*>(x + (size_t)n * 32);
#pragma unroll
        for (int q = 0; q < 8; ++q) {
            float4 v = x4[q];
            xr[4 * q] = v.x; xr[4 * q + 1] = v.y; xr[4 * q + 2] = v.z; xr[4 * q + 3] = v.w;
        }
        for (int jl = 0; jl < 32; jl += 2) {
            float pv[2], qv[2];
#pragma unroll
            for (int m = 0; m < 2; ++m) {
                int j = jl + m;
                float a = b1[jbase + j], q = 0.f;
                const f32x4* wa4 = (const f32x4*)(sWTa + j * 32);
                const f32x4* wb4 = (const f32x4*)(sWTb + j * 32);
#pragma unroll
                for (int k4 = 0; k4 < 8; ++k4) {
                    f32x4 wa = wa4[k4];
                    f32x4 wb = wb4[k4];
#pragma unroll
                    for (int e = 0; e < 4; ++e) {
                        a = fmaf(xr[4 * k4 + e], wa[e], a);
                        q = fmaf(xr[4 * k4 + e], wb[e], q);
                    }
                }
                pv[m] = a; qv[m] = q;
            }
            pw[jl >> 1] = pkrtz(pv[0], pv[1]);
            qw[jl >> 1] = pkrtz(qv[0], qv[1]);
        }
    }
    __syncthreads();   // weights dead; smem re-used as staging

    u32* sP = smem;            // [64][17] padded
    u32* sQ = smem + 1088;
    for (int r = 0; r < 4; ++r) {
        if ((tid >> 6) == r && n < N) {
            int row = tid & 63;
#pragma unroll
            for (int i = 0; i < 16; ++i) {
                sP[row * 17 + i] = pw[i];
                sQ[row * 17 + i] = qw[i];
            }
        }
        __syncthreads();
        int nodebase = nodeblk * 256 + r * 64;
        for (int w = tid; w < 1024; w += 256) {
            int node = nodebase + (w >> 4);
            if (node < N) {
                size_t base = (size_t)node * 32 + jhalf * 16 + (w & 15);
                Pb[base] = sP[(w >> 4) * 17 + (w & 15)];
                Qb[base] = sQ[(w >> 4) * 17 + (w & 15)];
            }
        }
        __syncthreads();
    }
}

// ---------- partial scan, 2048 items/block (8/thread) + block-sum scan (for g1) ----------
__global__ __launch_bounds__(256) void k_scan1(const u32* __restrict__ deg, u32* __restrict__ cursor,
                                               u32* __restrict__ bsum, int M) {
    __shared__ u32 sh[256];
    int t = threadIdx.x;
    int base = blockIdx.x * 2048 + t * 8;
    u32 v[8];
    if (base + 7 < M) {
        uint4 a = *reinterpret_cast<const uint4*>(deg + base);
        uint4 b = *reinterpret_cast<const uint4*>(deg + base + 4);
        v[0] = a.x; v[1] = a.y; v[2] = a.z; v[3] = a.w;
        v[4] = b.x; v[5] = b.y; v[6] = b.z; v[7] = b.w;
    } else {
#pragma unroll
        for (int i = 0; i < 8; ++i) v[i] = (base + i < M) ? deg[base + i] : 0;
    }
    u32 s = 0;
#pragma unroll
    for (int i = 0; i < 8; ++i) s += v[i];
    sh[t] = s; __syncthreads();
    u32 acc = s;
    for (int off = 1; off < 256; off <<= 1) {
        u32 add = (t >= off) ? sh[t - off] : 0;
        __syncthreads();
        acc += add; sh[t] = acc;
        __syncthreads();
    }
    u32 run = acc - s;
#pragma unroll
    for (int i = 0; i < 8; ++i) {
        if (base + i < M) cursor[base + i] = run;
        run += v[i];
    }
    if (t == 255) bsum[blockIdx.x] = acc;
}

__global__ __launch_bounds__(256) void k_scan2(const u32* __restrict__ bsum, u32* __restrict__ bsumX, int nb) {
    __shared__ u32 sh[256];
    int t = threadIdx.x;
    u32 v = (t < nb) ? bsum[t] : 0;
    sh[t] = v; __syncthreads();
    u32 acc = v;
    for (int off = 1; off < 256; off <<= 1) {
        u32 add = (t >= off) ? sh[t - off] : 0;
        __syncthreads();
        acc += add; sh[t] = acc;
        __syncthreads();
    }
    if (t < nb) bsumX[t] = acc - v;
}

// ---------- K_sp1: 1024-thread blocks, scatter src|local7<<17 into 128-buckets ----------
__global__ __launch_bounds__(1024) void k_sp1(const int* __restrict__ ei,
                                              const u32* __restrict__ g1cur, const u32* __restrict__ bsumX1,
                                              u32* __restrict__ sorted, int E, int NSB1, int npc) {
    __shared__ u32 sb[1024], cnt[1024];
    int tid = threadIdx.x;
    int c = (int)blockIdx.x;
    for (int s = tid; s < NSB1; s += 1024) {
        size_t idx = (size_t)s * npc + c;
        sb[s] = g1cur[idx] + bsumX1[idx >> 11];
        cnt[s] = 0;
    }
    __syncthreads();
    int s0 = c * CHP, end = min(E, s0 + CHP);
    int nq = (end - s0) >> 2;
    const int4* d4p = (const int4*)(ei + (size_t)E + s0);
    const int4* s4p = (const int4*)(ei + s0);
    for (int qi = tid; qi < nq; qi += 1024) {
        int4 d4 = d4p[qi];
        int4 s4 = s4p[qi];
        int dd[4] = {d4.x, d4.y, d4.z, d4.w};
        int ss[4] = {s4.x, s4.y, s4.z, s4.w};
#pragma unroll
        for (int u = 0; u < 4; ++u) {
            int s = dd[u] >> SH1;
            u32 r = atomicAdd(&cnt[s], 1u);
            sorted[sb[s] + r] = (u32)ss[u] | ((u32)(dd[u] & (NPB1 - 1)) << 17);
        }
    }
}

// ---------- K_sp2: per-128-bucket refine into 4 sub-buckets; self-derives bases, emits base32 ----------
// output record: src (17b) | local5 (bits 17..21)
__global__ __launch_bounds__(256) void k_sp2(const u32* __restrict__ sorted,
                                             const u32* __restrict__ g1cur, const u32* __restrict__ bsumX1,
                                             u32* __restrict__ sorted2, u32* __restrict__ base32,
                                             int E, int NSB1, int npc) {
    __shared__ u32 sb[4];
    __shared__ u32 cnt[4];
    int b = (int)blockIdx.x;
    int tid = threadIdx.x;

    size_t i0 = (size_t)b * npc;
    u32 start = g1cur[i0] + bsumX1[i0 >> 11];
    u32 bend;
    if (b + 1 < NSB1) {
        size_t i1 = (size_t)(b + 1) * npc;
        bend = g1cur[i1] + bsumX1[i1 >> 11];
    } else {
        bend = (u32)E;
    }

    if (tid < 4) cnt[tid] = 0;
    __syncthreads();

    // pass A: count sub-buckets
    for (u32 i = start + tid; i < bend; i += 256) {
        u32 rec = sorted[i];
        atomicAdd(&cnt[(rec >> 22) & 3u], 1u);
    }
    __syncthreads();

    if (tid == 0) {
        u32 run = start;
#pragma unroll
        for (int q = 0; q < 4; ++q) {
            sb[q] = run;
            base32[b * 4 + q] = run;
            run += cnt[q];
            cnt[q] = 0;
        }
    }
    __syncthreads();

    // pass B: ballot-ranked scatter (coalesced reads, contiguous writes per sub)
    for (u32 i0b = start; i0b < bend; i0b += 256) {
        u32 i = i0b + tid;
        bool vld = i < bend;
        u32 rec = vld ? sorted[i] : 0u;
        int q = vld ? (int)((rec >> 22) & 3u) : -1;
#pragma unroll
        for (int qq = 0; qq < 4; ++qq) {
            unsigned long long m = __ballot(q == qq);
            if (m) {
                int prefix = __popcll(m & ((1ull << (tid & 63)) - 1ull));
                u32 wb;
                if ((tid & 63) == 0) wb = atomicAdd(&cnt[qq], (u32)__popcll(m));
                wb = __shfl(wb, 0, 64);
                if (q == qq) sorted2[sb[qq] + wb + prefix] = rec & 0x3FFFFFu;
            }
        }
    }
}

// ---------- K_bucket: one 512-thread block (8 waves) per 32-node bucket ----------
// P rows staged in LDS (XOR-swizzled); depth-2 pipelined Q gather; f16 packed-math h;
// MFMA f16 + LDS max-agg (4KB) + fused decode/store
// A-frag (16x16x32 f16): lane l holds A[row=l&15][k=(l>>4)*8 + j]
// C/D (m89-verified, dtype-independent): lane l, reg i -> D[row=(l>>4)*4+i][col=l&15]
__global__ __launch_bounds__(512) void k_bucket(
    const u32* __restrict__ Pb, const u32* __restrict__ Qb,
    const u32* __restrict__ sorted2, const u32* __restrict__ base32,
    const float* __restrict__ W2, const float* __restrict__ b2,
    float* __restrict__ out, int E, int N, int NSB2)
{
    __shared__ u32 agg[NPB2 * 32];   // 4 KB, encoded-u32 max, 0 = "untouched"
    __shared__ u32 sPb[NPB2 * 32];   // 4 KB, P rows, group-XOR-swizzled
    int b = (int)blockIdx.x;
    int tid = threadIdx.x;
    int nodebase = b << SH2;

    for (int i = tid; i < NPB2 * 32; i += 512) agg[i] = 0u;
    // stage P rows: group g (4 words) of row loc stored at group (g ^ (loc&7))
    for (int i = tid; i < NPB2 * 32; i += 512) {
        int loc = i >> 5, w = i & 31;
        int node = nodebase + loc;
        u32 v = (node < N) ? Pb[(size_t)node * 32 + w] : 0u;
        sPb[loc * 32 + ((((w >> 2) ^ (loc & 7)) << 2) | (w & 3))] = v;
    }

    int lane = tid & 63;
    int wid = tid >> 6;            // 0..7
    int n = lane & 15;
    int kc = lane >> 4;

    // W2 resident as 4 f16 B-fragments
    half8v b00, b01, b10, b11;
#pragma unroll
    for (int j = 0; j < 8; ++j) {
        int k = kc * 8 + j;
        b00[j] = (_Float16)W2[k * 32 + n];
        b01[j] = (_Float16)W2[(k + 32) * 32 + n];
        b10[j] = (_Float16)W2[k * 32 + n + 16];
        b11[j] = (_Float16)W2[(k + 32) * 32 + n + 16];
    }

    u32 start = base32[b];
    u32 bend  = (b + 1 < NSB2) ? base32[b + 1] : (u32)E;
    int ntiles = ((int)(bend - start) + 15) >> 4;

    __syncthreads();   // agg + sPb ready

    int t = wid;
    u32 slotA = start + (u32)t * 16u + (u32)n;
    u32 recA = 0;
    uint4 qA0, qA1;
    if (t < ntiles) {   // wave-uniform branch
        u32 sl = slotA < bend ? slotA : bend - 1;
        recA = sorted2[sl];
        int src = (int)(recA & 0x1FFFFu);
        const u32* qr = Qb + (size_t)src * 32;
        qA0 = *(const uint4*)(qr + kc * 4);
        qA1 = *(const uint4*)(qr + 16 + kc * 4);
    }

    for (; t < ntiles; t += 8) {
        // ---- prefetch next tile's rec + Q for this wave (clamped-safe) ----
        u32 slotB = start + (u32)(t + 8) * 16u + (u32)n;
        u32 slB = slotB < bend ? slotB : bend - 1;
        u32 recB = sorted2[slB];
        int srcB = (int)(recB & 0x1FFFFu);
        const u32* qrB = Qb + (size_t)srcB * 32;
        uint4 qB0 = *(const uint4*)(qrB + kc * 4);
        uint4 qB1 = *(const uint4*)(qrB + 16 + kc * 4);

        // ---- compute current tile ----
        bool valid = slotA < bend;
        int locA = (int)(recA >> 17);
        int local = valid ? locA : -1;

        // P from LDS (swizzled groups; 16 lanes spread over 8 bank-groups)
        const u32* pr = sPb + locA * 32;
        uint4 pA0 = *(const uint4*)(pr + ((kc ^ (locA & 7)) << 2));
        uint4 pA1 = *(const uint4*)(pr + (((4 + kc) ^ (locA & 7)) << 2));

        // h = ReLU(P + Q) in packed f16: 2 VALU per u32
        u32x4 aw0, aw1;
        aw0[0] = pk_addrelu(pA0.x, qA0.x);
        aw0[1] = pk_addrelu(pA0.y, qA0.y);
        aw0[2] = pk_addrelu(pA0.z, qA0.z);
        aw0[3] = pk_addrelu(pA0.w, qA0.w);
        aw1[0] = pk_addrelu(pA1.x, qA1.x);
        aw1[1] = pk_addrelu(pA1.y, qA1.y);
        aw1[2] = pk_addrelu(pA1.z, qA1.z);
        aw1[3] = pk_addrelu(pA1.w, qA1.w);
        half8v a0 = __builtin_bit_cast(half8v, aw0);
        half8v a1 = __builtin_bit_cast(half8v, aw1);

        f32x4 d0 = {0.f, 0.f, 0.f, 0.f};
        f32x4 d1 = {0.f, 0.f, 0.f, 0.f};
        d0 = __builtin_amdgcn_mfma_f32_16x16x32_f16(a0, b00, d0, 0, 0, 0);
        d0 = __builtin_amdgcn_mfma_f32_16x16x32_f16(a1, b01, d0, 0, 0, 0);
        d1 = __builtin_amdgcn_mfma_f32_16x16x32_f16(a0, b10, d1, 0, 0, 0);
        d1 = __builtin_amdgcn_mfma_f32_16x16x32_f16(a1, b11, d1, 0, 0, 0);

        // rows owned by this lane: r = kc*4 + i; row r's record lives in lane r
#pragma unroll
        for (int i = 0; i < 4; ++i) {
            int r = kc * 4 + i;
            int lr = __shfl(local, r, 64);
            if (lr >= 0) {
                int sw = (lr & 1) << 4;
                atomicMax(&agg[(lr << 5) + (n ^ sw)], enc_f32(d0[i]));
                atomicMax(&agg[(lr << 5) + ((n + 16) ^ sw)], enc_f32(d1[i]));
            }
        }

        // ---- rotate ----
        slotA = slotB; recA = recB;
        qA0 = qB0; qA1 = qB1;
    }

    __syncthreads();
    // fused decode + b2 + empty->0; exclusive bucket ownership -> plain coalesced store
    for (int i = tid; i < NPB2 * 32; i += 512) {
        int local = i >> 5, c = i & 31;
        int node = nodebase + local;
        if (node < N) {
            u32 u = agg[(local << 5) + (c ^ ((local & 1) << 4))];
            out[(size_t)node * 32 + c] = u ? (dec_f32(u) + b2[c]) : 0.f;
        }
    }
}

// ---------- fallback (round-1 style) ----------
__global__ __launch_bounds__(256) void fb_edge(const float* __restrict__ x, const int* __restrict__ ei,
                                               const float* __restrict__ W1, const float* __restrict__ b1,
                                               const float* __restrict__ W2, const float* __restrict__ b2,
                                               u32* __restrict__ out, int E) {
    int e = blockIdx.x * 256 + threadIdx.x;
    if (e >= E) return;
    int src = ei[e], dst = ei[E + e];
    float m[64];
    const float4* xi4 = reinterpret_cast<const float4*>(x + (size_t)dst * 32);
    const float4* xj4 = reinterpret_cast<const float4*>(x + (size_t)src * 32);
#pragma unroll
    for (int q = 0; q < 8; ++q) {
        float4 a = xi4[q], b = xj4[q];
        m[q * 4] = a.x; m[q * 4 + 1] = a.y; m[q * 4 + 2] = a.z; m[q * 4 + 3] = a.w;
        m[32 + q * 4] = b.x - a.x; m[32 + q * 4 + 1] = b.y - a.y;
        m[32 + q * 4 + 2] = b.z - a.z; m[32 + q * 4 + 3] = b.w - a.w;
    }
    float acc[32];
#pragma unroll
    for (int c = 0; c < 32; ++c) acc[c] = b2[c];
    for (int j = 0; j < 64; ++j) {
        float h = b1[j];
#pragma unroll
        for (int k = 0; k < 64; ++k) h = fmaf(m[k], W1[k * 64 + j], h);
        h = fmaxf(h, 0.0f);
#pragma unroll
        for (int c = 0; c < 32; ++c) acc[c] = fmaf(h, W2[j * 32 + c], acc[c]);
    }
    u32* o = out + (size_t)dst * 32;
#pragma unroll
    for (int c = 0; c < 32; ++c) atomicMax(o + c, enc_f32(acc[c]));
}
__global__ __launch_bounds__(256) void fb_decode(u32* __restrict__ buf, int n) {
    int i = blockIdx.x * 256 + threadIdx.x;
    if (i >= n) return;
    u32 u = buf[i];
    reinterpret_cast<float*>(buf)[i] = u ? dec_f32(u) : 0.f;
}

extern "C" void kernel_launch(void* const* d_in, const int* in_sizes, int n_in,
                              void* d_out, int out_size, void* d_ws, size_t ws_size,
                              hipStream_t stream) {
    const float* x  = (const float*)d_in[0];
    const int*   ei = (const int*)d_in[1];
    const float* W1 = (const float*)d_in[2];
    const float* b1 = (const float*)d_in[3];
    const float* W2 = (const float*)d_in[4];
    const float* b2 = (const float*)d_in[5];

    int N = in_sizes[0] / 32;
    int E = in_sizes[1] / 2;
    int NSB1 = (N + NPB1 - 1) >> SH1;           // 782 sort buckets
    int NSB2 = NSB1 * 4;                        // 3128 agg buckets
    int npc = (E + CHP - 1) / CHP;              // 391 chunks
    int M1  = NSB1 * npc;                       // flat hist (305,762)
    int nb1 = (M1 + 2047) / 2048;               // 150 scan blocks

    // workspace layout (256B aligned)
    char* ws = (char*)d_ws;
    size_t off = 0;
    auto alloc = [&](size_t bytes) { char* p = ws + off; off += (bytes + 255) & ~(size_t)255; return p; };
    u32*   Pb      = (u32*)alloc((size_t)N * 32 * 4);
    u32*   Qb      = (u32*)alloc((size_t)N * 32 * 4);
    u32*   g1      = (u32*)alloc((size_t)M1 * 4);
    u32*   g1cur   = (u32*)alloc((size_t)M1 * 4);
    u32*   bsum1   = (u32*)alloc(256 * 4);
    u32*   bsumX1  = (u32*)alloc(256 * 4);
    u32*   base32  = (u32*)alloc((size_t)(NSB2 + 1) * 4);
    u32*   sorted  = (u32*)alloc((size_t)E * 4);
    u32*   sorted2 = (u32*)alloc((size_t)E * 4);
    // guards: LDS table sizes, 17b src, quad streams, scan width
    bool fits = (off <= ws_size) && (NSB1 <= 1024) &&
                (N < (1 << 17)) && ((E & 3) == 0) && (nb1 <= 256);

    if (!fits) {
        hipMemsetAsync(d_out, 0, (size_t)out_size * 4, stream);
        int be = (E + 255) / 256;
        fb_edge<<<be, 256, 0, stream>>>(x, ei, W1, b1, W2, b2, (u32*)d_out, E);
        fb_decode<<<(out_size + 255) / 256, 256, 0, stream>>>((u32*)d_out, out_size);
        return;
    }

    int pq_blocks = 2 * ((N + 255) / 256);      // j-split: 2 blocks per 256 nodes
    k_pq_hist<<<npc + pq_blocks, 256, 0, stream>>>(x, W1, b1, ei, Pb, Qb, g1, N, E, NSB1, npc);

    k_scan1<<<nb1, 256, 0, stream>>>(g1, g1cur, bsum1, M1);
    k_scan2<<<1, 256, 0, stream>>>(bsum1, bsumX1, nb1);

    k_sp1<<<npc, 1024, 0, stream>>>(ei, g1cur, bsumX1, sorted, E, NSB1, npc);

    k_sp2<<<NSB1, 256, 0, stream>>>(sorted, g1cur, bsumX1, sorted2, base32, E, NSB1, npc);

    k_bucket<<<NSB2, 512, 0, stream>>>(Pb, Qb, sorted2, base32, W2, b2,
                                       (float*)d_out, E, N, NSB2);
}